// Round 1
// baseline (154.835 us; speedup 1.0000x reference)
//
#include <hip/hip_runtime.h>
#include <hip/hip_bf16.h>

#define Bv 32
#define Dv 512
#define Kv 64
#define Nv 1024
#define EPSv 1e-12f

typedef __attribute__((ext_vector_type(8))) short bf16x8;
typedef __attribute__((ext_vector_type(4))) float f32x4;

// fp32 -> bf16 (RNE), bit-level
__device__ __forceinline__ unsigned short f2b(float f) {
  union { float f; unsigned u; } v; v.f = f;
  unsigned r = v.u + 0x7fffu + ((v.u >> 16) & 1u);
  return (unsigned short)(r >> 16);
}
__device__ __forceinline__ unsigned pack2(float a, float b) {
  return (unsigned)f2b(a) | ((unsigned)f2b(b) << 16);
}

// ---------------------------------------------------------------------------
// Kernel W: convert conv_w (K x D fp32) -> bf16. 32 blocks x 256 thr.
// ---------------------------------------------------------------------------
__global__ __launch_bounds__(256) void wconv(const float* __restrict__ w,
                                             unsigned short* __restrict__ wbf) {
  int i = (blockIdx.x * 256 + threadIdx.x) * 4;
  float4 v = *(const float4*)&w[i];
  uint2 o = make_uint2(pack2(v.x, v.y), pack2(v.z, v.w));
  *(uint2*)&wbf[i] = o;
}

// ---------------------------------------------------------------------------
// Kernel 1 (fused T+A), R6:
//  - NO xbf writeback (vlad kernel re-reads fp32 x from L3 instead)
//  - staging LDS writes rotated by s=(lo>>1)&3 to break the 8-way bank
//    conflict (banks 16(lo&1)+4((j+s)&3)+h2 -> 32 distinct, 2 lanes/bank)
// per (b, 64-n tile):
//  - stage x fp32 [512d x 64n] -> LDS xT[n][d] bf16 (pitch 520)
//  - scores GEMM 64k x 64n via MFMA (A from wbf L2, B ds_read_b128)
//  - softmax over k via shuffle + small LDS cross-wave reductions
//  - write assign bf16 + asum atomics
// Grid (N/64, B) = (16, 32) = 512 blocks, 512 threads (8 waves).
// LDS ~68.6 KB -> 2 blocks/CU, 16 waves/CU.
// ---------------------------------------------------------------------------
__global__ __launch_bounds__(512) void fused_scores(
    const float* __restrict__ x, const unsigned short* __restrict__ wbf,
    unsigned short* __restrict__ assign, float* __restrict__ asum) {
  __shared__ unsigned short xT[64 * 520];   // [n][d], pitch 520 shorts (1040B)
  __shared__ float redmax[4][64];
  __shared__ float redsum[4][64];

  const int t = threadIdx.x;   // 0..511
  const int b = blockIdx.y;
  const int n0 = blockIdx.x * 64;

  // ---------------- staging ----------------
  {
    const int lo = t & 15;     // n-quad
    const int hi = t >> 4;     // 0..31 (d-pair subindex)
    const int s = (lo >> 1) & 3;   // write-rotation amount (bank spread)
    const float* xb = x + (size_t)b * Dv * Nv + n0;
#pragma unroll
    for (int r = 0; r < 8; r++) {
      int d = (hi + 32 * r) * 2;        // even d row; covers 0..510
      int n4 = lo * 4;
      float4 v0 = *(const float4*)&xb[(size_t)d * Nv + n4];
      float4 v1 = *(const float4*)&xb[(size_t)(d + 1) * Nv + n4];
      // LDS xT: dword at [n][d] = (x[d][n], x[d+1][n]); d even -> aligned
      unsigned w0 = pack2(v0.x, v1.x);
      unsigned w1 = pack2(v0.y, v1.y);
      unsigned w2 = pack2(v0.z, v1.z);
      unsigned w3 = pack2(v0.w, v1.w);
      // rotate data+row-offset by s: instruction j writes row n4+((j+s)&3)
      unsigned a0 = (s & 1) ? w1 : w0, a1 = (s & 1) ? w2 : w1,
               a2 = (s & 1) ? w3 : w2, a3 = (s & 1) ? w0 : w3;
      unsigned b0 = (s & 2) ? a2 : a0, b1 = (s & 2) ? a3 : a1,
               b2 = (s & 2) ? a0 : a2, b3 = (s & 2) ? a1 : a3;
      *(unsigned*)&xT[(n4 + ((0 + s) & 3)) * 520 + d] = b0;
      *(unsigned*)&xT[(n4 + ((1 + s) & 3)) * 520 + d] = b1;
      *(unsigned*)&xT[(n4 + ((2 + s) & 3)) * 520 + d] = b2;
      *(unsigned*)&xT[(n4 + ((3 + s) & 3)) * 520 + d] = b3;
    }
  }
  __syncthreads();

  // ---------------- scores GEMM ----------------
  const int wv = t >> 6;        // 0..7
  const int lane = t & 63;
  const int q = lane >> 4;
  const int m = lane & 15;
  const int k16 = wv & 3;       // k-tile
  const int nsub = wv >> 2;     // n-half: cols [nsub*32, +32)

  f32x4 acc0 = {0.f, 0.f, 0.f, 0.f};
  f32x4 acc1 = {0.f, 0.f, 0.f, 0.f};

  const unsigned short* wp = wbf + (size_t)(k16 * 16 + m) * Dv + q * 8;
  const unsigned short* l0 = &xT[(nsub * 32 + m) * 520 + q * 8];
  const unsigned short* l1 = l0 + 16 * 520;

#pragma unroll
  for (int d0 = 0; d0 < Dv; d0 += 32) {
    bf16x8 af = *(const bf16x8*)(wp + d0);
    bf16x8 bf0 = *(const bf16x8*)(l0 + d0);
    bf16x8 bf1 = *(const bf16x8*)(l1 + d0);
    acc0 = __builtin_amdgcn_mfma_f32_16x16x32_bf16(af, bf0, acc0, 0, 0, 0);
    acc1 = __builtin_amdgcn_mfma_f32_16x16x32_bf16(af, bf1, acc1, 0, 0, 0);
  }

  // ---------------- softmax over k (64) ----------------
  float m0 = fmaxf(fmaxf(acc0[0], acc0[1]), fmaxf(acc0[2], acc0[3]));
  float m1 = fmaxf(fmaxf(acc1[0], acc1[1]), fmaxf(acc1[2], acc1[3]));
  m0 = fmaxf(m0, __shfl_xor(m0, 16)); m0 = fmaxf(m0, __shfl_xor(m0, 32));
  m1 = fmaxf(m1, __shfl_xor(m1, 16)); m1 = fmaxf(m1, __shfl_xor(m1, 32));
  if (q == 0) {
    redmax[k16][nsub * 32 + m] = m0;
    redmax[k16][nsub * 32 + 16 + m] = m1;
  }
  __syncthreads();
  const int c0 = nsub * 32 + m, c1 = c0 + 16;
  float mc0 = fmaxf(fmaxf(redmax[0][c0], redmax[1][c0]), fmaxf(redmax[2][c0], redmax[3][c0]));
  float mc1 = fmaxf(fmaxf(redmax[0][c1], redmax[1][c1]), fmaxf(redmax[2][c1], redmax[3][c1]));

  float e0[4], e1[4];
  float s0 = 0.f, s1 = 0.f;
#pragma unroll
  for (int r = 0; r < 4; r++) {
    e0[r] = __expf(acc0[r] - mc0); s0 += e0[r];
    e1[r] = __expf(acc1[r] - mc1); s1 += e1[r];
  }
  s0 += __shfl_xor(s0, 16); s0 += __shfl_xor(s0, 32);
  s1 += __shfl_xor(s1, 16); s1 += __shfl_xor(s1, 32);
  if (q == 0) {
    redsum[k16][c0] = s0;
    redsum[k16][c1] = s1;
  }
  __syncthreads();
  float sc0 = 1.0f / (redsum[0][c0] + redsum[1][c0] + redsum[2][c0] + redsum[3][c0]);
  float sc1 = 1.0f / (redsum[0][c1] + redsum[1][c1] + redsum[2][c1] + redsum[3][c1]);

  // ---------------- assign write + asum ----------------
  unsigned short* ab = assign + ((size_t)b * Kv + k16 * 16 + q * 4) * Nv + n0 + nsub * 32;
#pragma unroll
  for (int r = 0; r < 4; r++) {
    float v0 = e0[r] * sc0;
    float v1 = e1[r] * sc1;
    ab[(size_t)r * Nv + m] = f2b(v0);
    ab[(size_t)r * Nv + 16 + m] = f2b(v1);
    float p = v0 + v1;
    p += __shfl_xor(p, 1); p += __shfl_xor(p, 2);
    p += __shfl_xor(p, 4); p += __shfl_xor(p, 8);
    if (m == 0) atomicAdd(&asum[b * Kv + k16 * 16 + q * 4 + r], p);
  }
}

// ---------------------------------------------------------------------------
// Kernel 2 (R6): vlad[b,d,k] = sum_n x*assign - centers*asum via bf16 MFMA.
// Reads fp32 x directly (L3-resident after kernel 1) and converts to bf16
// in-register with the SAME RNE pack as kernel 1's scores input -> no xbf
// round-trip (-33.5 MB HBM writes, -32 MB reads).
// Block = 256 thr (4 waves, one per k16); each wave accumulates the FULL
// n=1024 -> no cross-wave LDS reduction, no __syncthreads, zero LDS.
// Grid (D/16, B) = (32, 32). Fuses colsq via atomics.
// ---------------------------------------------------------------------------
__global__ __launch_bounds__(256, 4) void vlad_mfma(
    const float* __restrict__ x, const unsigned short* __restrict__ assign,
    const float* __restrict__ centers, const float* __restrict__ asum,
    float* __restrict__ vlad, float* __restrict__ colsq) {
  const int t = threadIdx.x;
  const int b = blockIdx.y;
  const int d0 = blockIdx.x * 16;
  const int ksub = t >> 6;           // wave 0..3 -> k-tile
  const int lane = t & 63;
  const int q = lane >> 4;
  const int m = lane & 15;
  const int k16 = ksub * 16;

  const float* xp = x + ((size_t)b * Dv + d0 + m) * Nv + q * 8;
  const unsigned short* ap = assign + ((size_t)b * Kv + k16 + m) * Nv + q * 8;

  f32x4 acc = {0.f, 0.f, 0.f, 0.f};
#pragma unroll
  for (int n = 0; n < Nv; n += 32) {
    float4 f0 = *(const float4*)(xp + n);
    float4 f1 = *(const float4*)(xp + n + 4);
    bf16x8 av = *(const bf16x8*)(ap + n);
    bf16x8 xv;
    unsigned* xu = (unsigned*)&xv;
    xu[0] = pack2(f0.x, f0.y);
    xu[1] = pack2(f0.z, f0.w);
    xu[2] = pack2(f1.x, f1.y);
    xu[3] = pack2(f1.z, f1.w);
    acc = __builtin_amdgcn_mfma_f32_16x16x32_bf16(xv, av, acc, 0, 0, 0);
  }

  // C layout: col(k) = lane&15, row(d) = q*4 + r
  const int k = k16 + m;
  const float as = asum[b * Kv + k];
  float ss = 0.f;
#pragma unroll
  for (int r = 0; r < 4; r++) {
    int d = d0 + q * 4 + r;
    float val = acc[r] - centers[d * Kv + k] * as;
    vlad[((size_t)b * Dv + d) * Kv + k] = val;
    ss = fmaf(val, val, ss);
  }
  ss += __shfl_xor(ss, 16);
  ss += __shfl_xor(ss, 32);
  if (q == 0) atomicAdd(&colsq[b * Kv + k], ss);
}

// ---------------------------------------------------------------------------
// Kernel D: out = vlad * colscale[b,k] * bscale[b]; scales from colsq
// in-block. Grid 4096 x 256.
// ---------------------------------------------------------------------------
__global__ __launch_bounds__(256) void scale_kernel(
    const float* __restrict__ vlad, const float* __restrict__ colsq,
    float* __restrict__ out) {
  const int t = threadIdx.x;
  const size_t i = (size_t)blockIdx.x * 256 + t;
  const int b = (int)(i >> 15);  // D*K = 32768 per b
  __shared__ float scs[64];
  __shared__ float bsh;
  if (t < 64) {
    float tot = colsq[b * Kv + t];
    float sc = 1.0f / fmaxf(sqrtf(tot), EPSv);
    scs[t] = sc;
    float contrib = tot * sc * sc;
#pragma unroll
    for (int off = 32; off > 0; off >>= 1) contrib += __shfl_down(contrib, off);
    if (t == 0) bsh = 1.0f / fmaxf(sqrtf(contrib), EPSv);
  }
  __syncthreads();
  out[i] = vlad[i] * scs[i & 63] * bsh;
}

extern "C" void kernel_launch(void* const* d_in, const int* in_sizes, int n_in,
                              void* d_out, int out_size, void* d_ws, size_t ws_size,
                              hipStream_t stream) {
  const float* x = (const float*)d_in[0];        // [B, D, N]
  const float* w = (const float*)d_in[1];        // [K, D]
  const float* centers = (const float*)d_in[2];  // [D, K]
  float* out = (float*)d_out;                    // [B, D*K]

  char* ws = (char*)d_ws;
  unsigned short* assign = (unsigned short*)ws;               // [B][K][N] bf16, 4 MB
  float* vlad = (float*)(ws + 4194304);                       // [B][D][K] fp32, 4 MB
  unsigned short* wbf = (unsigned short*)(ws + 8388608);      // [K][D] bf16, 64 KB
  float* asum = (float*)(ws + 8454144);                       // B*K
  float* colsq = asum + Bv * Kv;                              // B*K (contiguous)

  hipMemsetAsync(asum, 0, (size_t)2 * Bv * Kv * sizeof(float), stream);

  wconv<<<32, 256, 0, stream>>>(w, wbf);
  fused_scores<<<dim3(Nv / 64, Bv), 512, 0, stream>>>(x, wbf, assign, asum);
  vlad_mfma<<<dim3(Dv / 16, Bv), 256, 0, stream>>>(x, assign, centers, asum, vlad, colsq);
  scale_kernel<<<(Bv * Dv * Kv) / 256, 256, 0, stream>>>(vlad, colsq, out);
}